// Round 2
// baseline (26118.417 us; speedup 1.0000x reference)
//
#include <hip/hip_runtime.h>
#include <stdint.h>

// RTRBM CD-1: bit-exact replication of the JAX-CPU reference.
// Sizes: V=784, H=500, T=256, B=256.
// RNG: threefry, PARTITIONABLE mode (jax >= 0.4.36 default).
#define NV 784
#define NH 500
#define TT 256
#define BB 256
#define KC 288   // Eigen MT blocking, AVX no-FMA: min((32K-384)/112,320) & ~7 = 288

// ---------------- threefry2x32 (JAX PRNG), exact ----------------
__device__ __forceinline__ void tf2x32(uint32_t ks0, uint32_t ks1,
                                       uint32_t x0, uint32_t x1,
                                       uint32_t& y0, uint32_t& y1) {
  uint32_t ks2 = ks0 ^ ks1 ^ 0x1BD11BDAu;
  x0 += ks0; x1 += ks1;
#define TFROT(r) { x0 += x1; x1 = (x1 << (r)) | (x1 >> (32 - (r))); x1 ^= x0; }
  TFROT(13) TFROT(15) TFROT(26) TFROT(6)
  x0 += ks1; x1 += ks2 + 1u;
  TFROT(17) TFROT(29) TFROT(16) TFROT(24)
  x0 += ks2; x1 += ks0 + 2u;
  TFROT(13) TFROT(15) TFROT(26) TFROT(6)
  x0 += ks0; x1 += ks1 + 3u;
  TFROT(17) TFROT(29) TFROT(16) TFROT(24)
  x0 += ks1; x1 += ks2 + 4u;
  TFROT(13) TFROT(15) TFROT(26) TFROT(6)
  x0 += ks2; x1 += ks0 + 5u;
#undef TFROT
  y0 = x0; y1 = x1;
}

// jax uniform [0,1): bitcast((bits>>9)|0x3F800000) - 1.0
__device__ __forceinline__ float jax_uniform(uint32_t bits) {
#pragma clang fp contract(off)
  float f = __uint_as_float((bits >> 9) | 0x3F800000u);
  return f - 1.0f;
}

// PARTITIONABLE random_bits, 32-bit, index j (< 2^32):
//   bits[j] = y0 ^ y1 of threefry(key; x0=0, x1=j)
__device__ __forceinline__ uint32_t draw_bits(uint32_t k0, uint32_t k1,
                                              uint32_t j) {
  uint32_t y0, y1;
  tf2x32(k0, k1, 0u, j, y0, y1);
  return y0 ^ y1;
}

// ---------------- XLA CPU exp (Cephes/Eigen poly, no FMA contraction) ----------------
__device__ __forceinline__ float xla_expf(float x) {
#pragma clang fp contract(off)
  float xc = fminf(fmaxf(x, -88.3762626647949f), 88.3762626647950f);
  float fx = floorf(xc * 1.44269504088896341f + 0.5f);
  float tmp = 0.693359375f * fx;
  float z = -2.12194440e-4f * fx;
  float xr = xc - tmp;
  xr = xr - z;
  z = xr * xr;
  float y = xr * 1.9875691500e-4f + 1.3981999507e-3f;
  y = y * xr + 8.3334519073e-3f;
  y = y * xr + 4.1665795894e-2f;
  y = y * xr + 1.6666665459e-1f;
  y = y * xr + 5.0000001201e-1f;
  y = y * z + xr;
  y = 1.0f + y;
  int e = (int)fx;
  float pow2 = __int_as_float((uint32_t)(e + 127) << 23);
  return y * pow2;
}

// XLA LogisticExpander: 1 / (1 + exp(-x))
__device__ __forceinline__ float xla_sigmoid(float x) {
#pragma clang fp contract(off)
  float e = xla_expf(-x);
  float d = 1.0f + e;
  return 1.0f / d;
}

// ---------------- per-step key derivation (PARTITIONABLE split) ----------------
// master = key(123) = (0,123)
// keys = split(master, 256): keys[t] = full pair of tf(master; 0, t)
// k1, k2 = split(keys[t]):   k1 = tf(kt; 0, 0),  k2 = tf(kt; 0, 1)
__global__ void init_keys(uint32_t* __restrict__ keys /* [256][4] */) {
  int t = threadIdx.x;
  if (t >= TT) return;
  uint32_t kt0, kt1;
  tf2x32(0u, 123u, 0u, (uint32_t)t, kt0, kt1);
  uint32_t a0, a1, b0, b1;
  tf2x32(kt0, kt1, 0u, 0u, a0, a1);  // k1
  tf2x32(kt0, kt1, 0u, 1u, b0, b1);  // k2
  keys[4 * t + 0] = a0;
  keys[4 * t + 1] = a1;
  keys[4 * t + 2] = b0;
  keys[4 * t + 3] = b1;
}

// ---------------- hidden step: pre = (W@v_t + U@r_lag) + bias; sample h ----------------
__global__ __launch_bounds__(BB) void hidden_step(
    const float* __restrict__ v, const float* __restrict__ W,
    const float* __restrict__ U, const float* __restrict__ b_h,
    const float* __restrict__ b_init, const uint32_t* __restrict__ keys,
    const float* __restrict__ r_old, float* __restrict__ r_new,
    float* __restrict__ h_buf, float* __restrict__ out_r, int t) {
#pragma clang fp contract(off)
  const int h = blockIdx.x;
  const int b = threadIdx.x;

  // W @ v_t : ascending-k chains in Eigen kc=288 panels (products exact: v binary)
  float accv = 0.0f;
  for (int p0 = 0; p0 < NV; p0 += KC) {
    const int pend = (p0 + KC < NV) ? (p0 + KC) : NV;
    float s = 0.0f;
    for (int k = p0; k < pend; ++k) {
      float w = W[h * NV + k];
      float x = v[(size_t)k * (TT * BB) + (size_t)t * BB + b];
      s = s + w * x;
    }
    accv = accv + s;
  }

  // U @ r_lag : mul-then-add (no-FMA Eigen), kc=288 panels
  float accu = 0.0f;
  for (int p0 = 0; p0 < NH; p0 += KC) {
    const int pend = (p0 + KC < NH) ? (p0 + KC) : NH;
    float s = 0.0f;
    for (int k = p0; k < pend; ++k) {
      float uu = U[h * NH + k];
      float rr = r_old[k * BB + b];
      s = s + uu * rr;
    }
    accu = accu + s;
  }

  float bias = (t == 0) ? b_init[h] : b_h[h];
  float pre = (accv + accu) + bias;   // add(add(dot1,dot2), bias)
  float p = xla_sigmoid(pre);

  // bernoulli(k1, p), shape (500,256): element j = h*256+b
  uint32_t j = (uint32_t)(h * BB + b);
  uint32_t bits = draw_bits(keys[4 * t + 0], keys[4 * t + 1], j);
  float u = jax_uniform(bits);
  float hm = (u < p) ? 1.0f : 0.0f;

  h_buf[j] = hm;
  r_new[j] = p;  // carry is r_data (the mean)
  out_r[(size_t)h * (TT * BB) + (size_t)t * BB + b] = hm;
}

// ---------------- visible step: pre = W.T@h + b_v; sample v ----------------
__global__ __launch_bounds__(BB) void visible_step(
    const float* __restrict__ W, const float* __restrict__ b_v,
    const uint32_t* __restrict__ keys, const float* __restrict__ h_buf,
    float* __restrict__ out_v, int t) {
#pragma clang fp contract(off)
  const int i = blockIdx.x;
  const int b = threadIdx.x;

  // W.T @ h : k over H=500, kc=288 panels (products exact: h binary)
  float acc = 0.0f;
  for (int p0 = 0; p0 < NH; p0 += KC) {
    const int pend = (p0 + KC < NH) ? (p0 + KC) : NH;
    float s = 0.0f;
    for (int k = p0; k < pend; ++k) {
      float w = W[k * NV + i];
      float hh = h_buf[k * BB + b];
      s = s + w * hh;
    }
    acc = acc + s;
  }

  float pre = acc + b_v[i];
  float p = xla_sigmoid(pre);

  // bernoulli(k2, p), shape (784,256): element j = i*256+b
  uint32_t j = (uint32_t)(i * BB + b);
  uint32_t bits = draw_bits(keys[4 * t + 2], keys[4 * t + 3], j);
  float u = jax_uniform(bits);
  out_v[(size_t)i * (TT * BB) + (size_t)t * BB + b] = (u < p) ? 1.0f : 0.0f;
}

extern "C" void kernel_launch(void* const* d_in, const int* in_sizes, int n_in,
                              void* d_out, int out_size, void* d_ws, size_t ws_size,
                              hipStream_t stream) {
  const float* v      = (const float*)d_in[0];
  const float* W      = (const float*)d_in[1];
  const float* U      = (const float*)d_in[2];
  const float* b_h    = (const float*)d_in[3];
  const float* b_v    = (const float*)d_in[4];
  const float* b_init = (const float*)d_in[5];

  float* out_v = (float*)d_out;                       // (784,256,256)
  float* out_r = out_v + (size_t)NV * TT * BB;        // (500,256,256)

  // workspace: r ping-pong (2 x 128000 f32), h_buf (128000 f32), keys (256*4 u32)
  float* r0 = (float*)d_ws;
  float* r1 = r0 + NH * BB;
  float* h_buf = r1 + NH * BB;
  uint32_t* keys = (uint32_t*)(h_buf + NH * BB);

  hipMemsetAsync(r0, 0, (size_t)NH * BB * sizeof(float), stream);  // r_lag(t=0) = 0
  init_keys<<<1, 256, 0, stream>>>(keys);

  for (int t = 0; t < TT; ++t) {
    float* r_old = (t & 1) ? r1 : r0;
    float* r_new = (t & 1) ? r0 : r1;
    hidden_step<<<NH, BB, 0, stream>>>(v, W, U, b_h, b_init, keys,
                                       r_old, r_new, h_buf, out_r, t);
    visible_step<<<NV, BB, 0, stream>>>(W, b_v, keys, h_buf, out_v, t);
  }
}

// Round 3
// 10981.334 us; speedup vs baseline: 2.3784x; 2.3784x over previous
//
#include <hip/hip_runtime.h>
#include <stdint.h>

// RTRBM CD-1: bit-exact replication of the JAX-CPU reference, restructured.
// Phase A: WV[t] = W @ v_t for all t (parallel, off critical path, chunked in ws)
// Phase B: per-t serial: pre = (WV + U@r_lag) + bias -> sigmoid -> sample (ballot-packed h)
// Phase C: all visible steps at once from bit-packed h.
// Sizes: V=784, H=500, T=256, B=256. RNG: threefry partitionable.
#define NV 784
#define NH 500
#define TT 256
#define BB 256
// Eigen MT blocking, AVX no-FMA: panels K=784 -> [288,288,208]; K=500 -> [288,212]

// ---------------- threefry2x32 (JAX PRNG), exact ----------------
__device__ __forceinline__ void tf2x32(uint32_t ks0, uint32_t ks1,
                                       uint32_t x0, uint32_t x1,
                                       uint32_t& y0, uint32_t& y1) {
  uint32_t ks2 = ks0 ^ ks1 ^ 0x1BD11BDAu;
  x0 += ks0; x1 += ks1;
#define TFROT(r) { x0 += x1; x1 = (x1 << (r)) | (x1 >> (32 - (r))); x1 ^= x0; }
  TFROT(13) TFROT(15) TFROT(26) TFROT(6)
  x0 += ks1; x1 += ks2 + 1u;
  TFROT(17) TFROT(29) TFROT(16) TFROT(24)
  x0 += ks2; x1 += ks0 + 2u;
  TFROT(13) TFROT(15) TFROT(26) TFROT(6)
  x0 += ks0; x1 += ks1 + 3u;
  TFROT(17) TFROT(29) TFROT(16) TFROT(24)
  x0 += ks1; x1 += ks2 + 4u;
  TFROT(13) TFROT(15) TFROT(26) TFROT(6)
  x0 += ks2; x1 += ks0 + 5u;
#undef TFROT
  y0 = x0; y1 = x1;
}

__device__ __forceinline__ float jax_uniform(uint32_t bits) {
#pragma clang fp contract(off)
  float f = __uint_as_float((bits >> 9) | 0x3F800000u);
  return f - 1.0f;
}

// PARTITIONABLE random_bits, 32-bit: bits[j] = y0 ^ y1 of threefry(key; 0, j)
__device__ __forceinline__ uint32_t draw_bits(uint32_t k0, uint32_t k1,
                                              uint32_t j) {
  uint32_t y0, y1;
  tf2x32(k0, k1, 0u, j, y0, y1);
  return y0 ^ y1;
}

// ---------------- XLA CPU exp (Cephes/Eigen poly, no FMA) ----------------
__device__ __forceinline__ float xla_expf(float x) {
#pragma clang fp contract(off)
  float xc = fminf(fmaxf(x, -88.3762626647949f), 88.3762626647950f);
  float fx = floorf(xc * 1.44269504088896341f + 0.5f);
  float tmp = 0.693359375f * fx;
  float z = -2.12194440e-4f * fx;
  float xr = xc - tmp;
  xr = xr - z;
  z = xr * xr;
  float y = xr * 1.9875691500e-4f + 1.3981999507e-3f;
  y = y * xr + 8.3334519073e-3f;
  y = y * xr + 4.1665795894e-2f;
  y = y * xr + 1.6666665459e-1f;
  y = y * xr + 5.0000001201e-1f;
  y = y * z + xr;
  y = 1.0f + y;
  int e = (int)fx;
  float pow2 = __int_as_float((uint32_t)(e + 127) << 23);
  return y * pow2;
}

__device__ __forceinline__ float xla_sigmoid(float x) {
#pragma clang fp contract(off)
  float e = xla_expf(-x);
  float d = 1.0f + e;
  return 1.0f / d;
}

// ---------------- key derivation (PARTITIONABLE split) ----------------
__global__ void init_keys(uint32_t* __restrict__ keys /* [256][4] */) {
  int t = threadIdx.x;
  if (t >= TT) return;
  uint32_t kt0, kt1;
  tf2x32(0u, 123u, 0u, (uint32_t)t, kt0, kt1);
  uint32_t a0, a1, b0, b1;
  tf2x32(kt0, kt1, 0u, 0u, a0, a1);  // k1
  tf2x32(kt0, kt1, 0u, 1u, b0, b1);  // k2
  keys[4 * t + 0] = a0;
  keys[4 * t + 1] = a1;
  keys[4 * t + 2] = b0;
  keys[4 * t + 3] = b1;
}

// ---------------- W transpose: WT[i][k] = W[k][i] ----------------
__global__ __launch_bounds__(256) void wt_kernel(const float* __restrict__ W,
                                                 float* __restrict__ WT) {
  const int i = blockIdx.x;           // 0..783
  for (int k = threadIdx.x; k < NH; k += 256)
    WT[(size_t)i * NH + k] = W[(size_t)k * NV + i];
}

// ---------------- Phase A: WV[tl][h][b] = (W @ v_t)[h][b], exact panels ----------------
#define HT_A 25   // 500/25 = 20 blocks per t
__global__ __launch_bounds__(256) void wv_gemm(
    const float* __restrict__ v, const float* __restrict__ W,
    float* __restrict__ wv, int t0) {
#pragma clang fp contract(off)
  const int b = threadIdx.x;
  const int h0 = blockIdx.x * HT_A;
  const int tl = blockIdx.y;
  const int t = t0 + tl;
  const float* vcol = v + (size_t)t * BB + b;   // element k: vcol[k * TT*BB]

  float acc[HT_A];
#pragma unroll
  for (int r = 0; r < HT_A; ++r) acc[r] = 0.0f;

  const int pb[4] = {0, 288, 576, 784};   // kc=288 panels
#pragma unroll 1
  for (int p = 0; p < 3; ++p) {
    float ps[HT_A];
#pragma unroll
    for (int r = 0; r < HT_A; ++r) ps[r] = 0.0f;
    const int k0 = pb[p], k1 = pb[p + 1];
#pragma unroll 4
    for (int k = k0; k < k1; ++k) {
      float x = vcol[(size_t)k * (TT * BB)];
#pragma unroll
      for (int r = 0; r < HT_A; ++r) {
        float w = W[(size_t)(h0 + r) * NV + k];
        ps[r] = ps[r] + w * x;
      }
    }
#pragma unroll
    for (int r = 0; r < HT_A; ++r) acc[r] = acc[r] + ps[r];
  }
#pragma unroll
  for (int r = 0; r < HT_A; ++r)
    wv[((size_t)tl * NH + (h0 + r)) * BB + b] = acc[r];
}

// ---------------- Phase B: serial hidden step ----------------
#define HT_B 2    // 500/2 = 250 blocks
__global__ __launch_bounds__(256) void hidden_wv(
    const float* __restrict__ wv, const float* __restrict__ U,
    const float* __restrict__ b_h, const float* __restrict__ b_init,
    const uint32_t* __restrict__ keys, const float* __restrict__ r_old,
    float* __restrict__ r_new, uint32_t* __restrict__ hbits,
    float* __restrict__ out_r, int t, int tl) {
#pragma clang fp contract(off)
  const int b = threadIdx.x;
  const int h0 = blockIdx.x * HT_B;

  float accu[HT_B];
#pragma unroll
  for (int r = 0; r < HT_B; ++r) accu[r] = 0.0f;

  const int pb[3] = {0, 288, 500};   // K=500 -> [288,212]
#pragma unroll 1
  for (int p = 0; p < 2; ++p) {
    float ps[HT_B];
#pragma unroll
    for (int r = 0; r < HT_B; ++r) ps[r] = 0.0f;
    const int k0 = pb[p], k1 = pb[p + 1];
#pragma unroll 8
    for (int k = k0; k < k1; ++k) {
      float rr = r_old[k * BB + b];
#pragma unroll
      for (int r = 0; r < HT_B; ++r) {
        float uu = U[(size_t)(h0 + r) * NH + k];
        ps[r] = ps[r] + uu * rr;
      }
    }
#pragma unroll
    for (int r = 0; r < HT_B; ++r) accu[r] = accu[r] + ps[r];
  }

  const uint32_t key0 = keys[4 * t + 0], key1 = keys[4 * t + 1];
#pragma unroll
  for (int r = 0; r < HT_B; ++r) {
    const int h = h0 + r;
    float bias = (t == 0) ? b_init[h] : b_h[h];
    float wvv = wv[((size_t)tl * NH + h) * BB + b];
    float pre = (wvv + accu[r]) + bias;
    float p = xla_sigmoid(pre);
    uint32_t j = (uint32_t)(h * BB + b);
    float u = jax_uniform(draw_bits(key0, key1, j));
    bool hm = (u < p);
    r_new[h * BB + b] = p;
    out_r[(size_t)h * (TT * BB) + (size_t)t * BB + b] = hm ? 1.0f : 0.0f;
    unsigned long long m = __ballot(hm);
    uint32_t* hw = hbits + ((size_t)t * NH + h) * 8;
    if ((b & 63) == 0)  hw[b >> 5] = (uint32_t)m;
    if ((b & 63) == 32) hw[b >> 5] = (uint32_t)(m >> 32);
  }
}

// ---------------- Phase C: all visible steps from packed h ----------------
#define IT_C 16   // 784/16 = 49 i-tiles
__global__ __launch_bounds__(256) void visible_big(
    const float* __restrict__ WT, const float* __restrict__ b_v,
    const uint32_t* __restrict__ keys, const uint32_t* __restrict__ hbits,
    float* __restrict__ out_v) {
#pragma clang fp contract(off)
  const int b = threadIdx.x;
  const int i0 = blockIdx.x * IT_C;
  const int t = blockIdx.y;
  const uint32_t sh = (uint32_t)(b & 31);
  const uint32_t* hb = hbits + (size_t)t * NH * 8 + (b >> 5);

  float acc[IT_C];
#pragma unroll
  for (int r = 0; r < IT_C; ++r) acc[r] = 0.0f;

  const int pb[3] = {0, 288, 500};   // K=500 -> [288,212]
#pragma unroll 1
  for (int p = 0; p < 2; ++p) {
    float ps[IT_C];
#pragma unroll
    for (int r = 0; r < IT_C; ++r) ps[r] = 0.0f;
    const int k0 = pb[p], k1 = pb[p + 1];
#pragma unroll 4
    for (int k = k0; k < k1; ++k) {
      uint32_t w32 = hb[(size_t)k * 8];
      bool on = ((w32 >> sh) & 1u) != 0u;
#pragma unroll
      for (int r = 0; r < IT_C; ++r) {
        float wt = WT[(size_t)(i0 + r) * NH + k];
        float term = on ? wt : 0.0f;   // == wt * h bit-exactly (h in {0,1})
        ps[r] = ps[r] + term;
      }
    }
#pragma unroll
    for (int r = 0; r < IT_C; ++r) acc[r] = acc[r] + ps[r];
  }

  const uint32_t key0 = keys[4 * t + 2], key1 = keys[4 * t + 3];
#pragma unroll
  for (int r = 0; r < IT_C; ++r) {
    const int i = i0 + r;
    float pre = acc[r] + b_v[i];
    float p = xla_sigmoid(pre);
    uint32_t j = (uint32_t)(i * BB + b);
    float u = jax_uniform(draw_bits(key0, key1, j));
    out_v[(size_t)i * (TT * BB) + (size_t)t * BB + b] = (u < p) ? 1.0f : 0.0f;
  }
}

// ---------------- Fallback (round-2 style) if ws too small ----------------
__global__ __launch_bounds__(BB) void hidden_step_full(
    const float* __restrict__ v, const float* __restrict__ W,
    const float* __restrict__ U, const float* __restrict__ b_h,
    const float* __restrict__ b_init, const uint32_t* __restrict__ keys,
    const float* __restrict__ r_old, float* __restrict__ r_new,
    float* __restrict__ h_buf, float* __restrict__ out_r, int t) {
#pragma clang fp contract(off)
  const int h = blockIdx.x;
  const int b = threadIdx.x;
  float accv = 0.0f;
  for (int p0 = 0; p0 < NV; p0 += 288) {
    const int pend = (p0 + 288 < NV) ? (p0 + 288) : NV;
    float s = 0.0f;
    for (int k = p0; k < pend; ++k)
      s = s + W[h * NV + k] * v[(size_t)k * (TT * BB) + (size_t)t * BB + b];
    accv = accv + s;
  }
  float accu = 0.0f;
  for (int p0 = 0; p0 < NH; p0 += 288) {
    const int pend = (p0 + 288 < NH) ? (p0 + 288) : NH;
    float s = 0.0f;
    for (int k = p0; k < pend; ++k)
      s = s + U[h * NH + k] * r_old[k * BB + b];
    accu = accu + s;
  }
  float bias = (t == 0) ? b_init[h] : b_h[h];
  float p = xla_sigmoid((accv + accu) + bias);
  uint32_t j = (uint32_t)(h * BB + b);
  float u = jax_uniform(draw_bits(keys[4 * t + 0], keys[4 * t + 1], j));
  float hm = (u < p) ? 1.0f : 0.0f;
  h_buf[j] = hm;
  r_new[j] = p;
  out_r[(size_t)h * (TT * BB) + (size_t)t * BB + b] = hm;
}

__global__ __launch_bounds__(BB) void visible_step_full(
    const float* __restrict__ W, const float* __restrict__ b_v,
    const uint32_t* __restrict__ keys, const float* __restrict__ h_buf,
    float* __restrict__ out_v, int t) {
#pragma clang fp contract(off)
  const int i = blockIdx.x;
  const int b = threadIdx.x;
  float acc = 0.0f;
  for (int p0 = 0; p0 < NH; p0 += 288) {
    const int pend = (p0 + 288 < NH) ? (p0 + 288) : NH;
    float s = 0.0f;
    for (int k = p0; k < pend; ++k)
      s = s + W[k * NV + i] * h_buf[k * BB + b];
    acc = acc + s;
  }
  float p = xla_sigmoid(acc + b_v[i]);
  uint32_t j = (uint32_t)(i * BB + b);
  float u = jax_uniform(draw_bits(keys[4 * t + 2], keys[4 * t + 3], j));
  out_v[(size_t)i * (TT * BB) + (size_t)t * BB + b] = (u < p) ? 1.0f : 0.0f;
}

extern "C" void kernel_launch(void* const* d_in, const int* in_sizes, int n_in,
                              void* d_out, int out_size, void* d_ws, size_t ws_size,
                              hipStream_t stream) {
  const float* v      = (const float*)d_in[0];
  const float* W      = (const float*)d_in[1];
  const float* U      = (const float*)d_in[2];
  const float* b_h    = (const float*)d_in[3];
  const float* b_v    = (const float*)d_in[4];
  const float* b_init = (const float*)d_in[5];

  float* out_v = (float*)d_out;                       // (784,256,256)
  float* out_r = out_v + (size_t)NV * TT * BB;        // (500,256,256)

  // ws layout: r0, r1, WT, hbits, keys, WV-chunk
  float* r0 = (float*)d_ws;
  float* r1 = r0 + (size_t)NH * BB;
  float* WT = r1 + (size_t)NH * BB;
  uint32_t* hbits = (uint32_t*)(WT + (size_t)NV * NH);
  uint32_t* keys = hbits + (size_t)TT * NH * 8;
  float* wv = (float*)(keys + TT * 4);

  const size_t fixed_bytes = (size_t)((char*)wv - (char*)d_ws);
  const size_t per_t = (size_t)NH * BB * sizeof(float);   // 512 KB
  int TC = 0;
  if (ws_size > fixed_bytes) {
    size_t tcs = (ws_size - fixed_bytes) / per_t;
    TC = (tcs >= TT) ? TT : (int)tcs;
  }

  hipMemsetAsync(r0, 0, (size_t)NH * BB * sizeof(float), stream);  // r_lag(0)=0
  init_keys<<<1, 256, 0, stream>>>(keys);

  if (TC >= 1) {
    wt_kernel<<<NV, 256, 0, stream>>>(W, WT);
    int t = 0;
    for (int c0 = 0; c0 < TT; c0 += TC) {
      const int tc = (c0 + TC <= TT) ? TC : (TT - c0);
      dim3 gA(NH / HT_A, tc);
      wv_gemm<<<gA, 256, 0, stream>>>(v, W, wv, c0);
      for (int tl = 0; tl < tc; ++tl, ++t) {
        float* r_old = (t & 1) ? r1 : r0;
        float* r_new = (t & 1) ? r0 : r1;
        hidden_wv<<<NH / HT_B, 256, 0, stream>>>(wv, U, b_h, b_init, keys,
                                                 r_old, r_new, hbits, out_r, t, tl);
      }
    }
    dim3 gC(NV / IT_C, TT);
    visible_big<<<gC, 256, 0, stream>>>(WT, b_v, keys, hbits, out_v);
  } else {
    // ws too small for even one timestep of WV: round-2 fallback
    float* h_buf = WT;   // reuse WT region (not used in fallback)
    for (int t = 0; t < TT; ++t) {
      float* r_old = (t & 1) ? r1 : r0;
      float* r_new = (t & 1) ? r0 : r1;
      hidden_step_full<<<NH, BB, 0, stream>>>(v, W, U, b_h, b_init, keys,
                                              r_old, r_new, h_buf, out_r, t);
      visible_step_full<<<NV, BB, 0, stream>>>(W, b_v, keys, h_buf, out_v, t);
    }
  }
}